// Round 3
// baseline (427.934 us; speedup 1.0000x reference)
//
#include <hip/hip_runtime.h>
#include <hip/hip_bf16.h>

// QuaternionLinear = one 8192x4096x4096 GEMM vs Hamilton-assembled W.
// Strategy: prep-convert x and W to bf16 in ws, then m97-structure 128^2
// MFMA GEMM with global_load_lds(16B) staging. Fallback (ws too small):
// identical GEMM with reg-staged fp32->bf16 conversion + on-the-fly W
// assembly (comp = p^q, sign from mask 0x428E).

#define M_DIM 8192
#define N_DIM 4096
#define K_DIM 4096
#define BM 128
#define BN 128
#define BK 64

typedef __attribute__((ext_vector_type(8))) short bf16x8;
typedef __attribute__((ext_vector_type(4))) float f32x4;
typedef __attribute__((ext_vector_type(8))) unsigned short ushort8;

static __device__ __forceinline__ unsigned short f2bf(float f) {
    unsigned int u = __float_as_uint(f);
    return (unsigned short)((u + 0x7fffu + ((u >> 16) & 1u)) >> 16);
}

static __device__ __forceinline__ unsigned short f2bf_sgn(float f, unsigned int sg) {
    unsigned int u = __float_as_uint(f) ^ sg;
    return (unsigned short)((u + 0x7fffu + ((u >> 16) & 1u)) >> 16);
}

// ---------------- prep: x (fp32) -> xb (bf16) ----------------
__global__ __launch_bounds__(256) void cvt_x_kernel(const float* __restrict__ x,
                                                    unsigned short* __restrict__ xb) {
    int i = (blockIdx.x * 256 + threadIdx.x) * 8;
    float4 a = *(const float4*)(x + i);
    float4 b = *(const float4*)(x + i + 4);
    ushort8 o;
    o[0] = f2bf(a.x); o[1] = f2bf(a.y); o[2] = f2bf(a.z); o[3] = f2bf(a.w);
    o[4] = f2bf(b.x); o[5] = f2bf(b.y); o[6] = f2bf(b.z); o[7] = f2bf(b.w);
    *(ushort8*)(xb + i) = o;
}

// ---------------- prep: assemble Hamilton W (bf16) ----------------
// Wb[o][i] = sign(p,q) * Wc[p^q][o&1023][i&1023],  p=o>>10, q=i>>10
// neg iff bit (p*4+q) of 0x428E is set.
__global__ __launch_bounds__(256) void prep_w_kernel(const float* __restrict__ Wr,
    const float* __restrict__ Wi, const float* __restrict__ Wj,
    const float* __restrict__ Wk, unsigned short* __restrict__ wb) {
    int row = blockIdx.x >> 1;
    int col = ((blockIdx.x & 1) * 256 + threadIdx.x) * 8;
    int p = row >> 10, q = col >> 10;
    int ci = p ^ q;
    const float* src = (ci == 0) ? Wr : (ci == 1) ? Wi : (ci == 2) ? Wj : Wk;
    unsigned int sg = ((0x428Eu >> (p * 4 + q)) & 1u) << 31;
    int so = (row & 1023) * 1024 + (col & 1023);
    float4 a = *(const float4*)(src + so);
    float4 b = *(const float4*)(src + so + 4);
    ushort8 o;
    o[0] = f2bf_sgn(a.x, sg); o[1] = f2bf_sgn(a.y, sg);
    o[2] = f2bf_sgn(a.z, sg); o[3] = f2bf_sgn(a.w, sg);
    o[4] = f2bf_sgn(b.x, sg); o[5] = f2bf_sgn(b.y, sg);
    o[6] = f2bf_sgn(b.z, sg); o[7] = f2bf_sgn(b.w, sg);
    *(ushort8*)(wb + row * 4096 + col) = o;
}

// ---------------- main GEMM: m97 structure (128^2, BK=64, 4 waves) --------
#define GLD16(gp, lp) __builtin_amdgcn_global_load_lds( \
    (const __attribute__((address_space(1))) void*)(gp), \
    (__attribute__((address_space(3))) void*)(lp), 16, 0, 0)

__global__ __launch_bounds__(256) void qgemm_bf16(const unsigned short* __restrict__ A,
    const unsigned short* __restrict__ B, const float* __restrict__ bias,
    float* __restrict__ out)
{
    __shared__ unsigned short As[BM * BK];  // 16 KB, linear (required by gload_lds)
    __shared__ unsigned short Bs[BN * BK];  // 16 KB

    // bijective XCD swizzle: 2048 blocks, 2048 % 8 == 0
    int bid = blockIdx.x;
    int cpx = gridDim.x >> 3;
    int wg = (bid & 7) * cpx + (bid >> 3);
    int brow = (wg >> 5) * BM;   // 64 row-tiles
    int bcol = (wg & 31) * BN;   // 32 col-tiles

    int tid = threadIdx.x;
    int lane = tid & 63;
    int wv = tid >> 6;
    int wm = (wv >> 1) << 6;     // wave owns 64x64 sub-tile
    int wn = (wv & 1) << 6;

    int fr = lane & 15;          // fragment row (A) / col-row (B^T)
    int fk = (lane >> 4) << 3;   // k-offset: lane holds 8 contiguous k

    f32x4 acc[4][4] = {};

    const unsigned short* ag = A + brow * K_DIM;
    const unsigned short* bg = B + bcol * K_DIM;

    for (int kt = 0; kt < K_DIM / BK; ++kt) {
        int k0 = kt * BK;
        __syncthreads();  // previous compute done before LDS overwrite
        #pragma unroll
        for (int i = 0; i < 4; ++i) {
            int c = i * 256 + tid;  // chunk: row = c>>3, 16B slot = c&7
            GLD16(ag + (c >> 3) * K_DIM + k0 + ((c & 7) << 3), &As[c << 3]);
        }
        #pragma unroll
        for (int i = 0; i < 4; ++i) {
            int c = i * 256 + tid;
            GLD16(bg + (c >> 3) * K_DIM + k0 + ((c & 7) << 3), &Bs[c << 3]);
        }
        __syncthreads();  // compiler drains vmcnt(0) here -> tiles ready

        #pragma unroll
        for (int ks = 0; ks < 2; ++ks) {
            bf16x8 af[4], bfr[4];
            #pragma unroll
            for (int m = 0; m < 4; ++m)
                af[m] = *(const bf16x8*)(&As[(wm + m * 16 + fr) * BK + ks * 32 + fk]);
            #pragma unroll
            for (int n = 0; n < 4; ++n)
                bfr[n] = *(const bf16x8*)(&Bs[(wn + n * 16 + fr) * BK + ks * 32 + fk]);
            #pragma unroll
            for (int m = 0; m < 4; ++m)
                #pragma unroll
                for (int n = 0; n < 4; ++n)
                    acc[m][n] = __builtin_amdgcn_mfma_f32_16x16x32_bf16(
                        af[m], bfr[n], acc[m][n], 0, 0, 0);
        }
    }

    // epilogue: C/D layout col=lane&15, row=(lane>>4)*4+reg (m89/m91 verified)
    int cr = (lane >> 4) << 2;
    int cc = lane & 15;
    #pragma unroll
    for (int n = 0; n < 4; ++n) {
        int col = bcol + wn + n * 16 + cc;
        float bv = bias[col];
        #pragma unroll
        for (int m = 0; m < 4; ++m) {
            int r0 = brow + wm + m * 16 + cr;
            #pragma unroll
            for (int r = 0; r < 4; ++r)
                out[(r0 + r) * N_DIM + col] = acc[m][n][r] + bv;
        }
    }
}

// ---------------- fallback: reg-staged, no workspace ----------------
__global__ __launch_bounds__(256) void qgemm_fb(const float* __restrict__ x,
    const float* __restrict__ Wr, const float* __restrict__ Wi,
    const float* __restrict__ Wj, const float* __restrict__ Wk,
    const float* __restrict__ bias, float* __restrict__ out)
{
    __shared__ unsigned short As[BM * BK];
    __shared__ unsigned short Bs[BN * BK];

    int bid = blockIdx.x;
    int cpx = gridDim.x >> 3;
    int wg = (bid & 7) * cpx + (bid >> 3);
    int brow = (wg >> 5) * BM;
    int bcol = (wg & 31) * BN;

    int tid = threadIdx.x;
    int lane = tid & 63;
    int wv = tid >> 6;
    int wm = (wv >> 1) << 6;
    int wn = (wv & 1) << 6;
    int fr = lane & 15;
    int fk = (lane >> 4) << 3;

    int p = bcol >> 10;  // row-block quadrant, uniform per block
    f32x4 acc[4][4] = {};

    for (int kt = 0; kt < K_DIM / BK; ++kt) {
        int k0 = kt * BK;
        int q = k0 >> 10;  // col-block quadrant, uniform per K-tile
        int ci = p ^ q;
        const float* wsrc = (ci == 0) ? Wr : (ci == 1) ? Wi : (ci == 2) ? Wj : Wk;
        unsigned int sg = ((0x428Eu >> (p * 4 + q)) & 1u) << 31;

        __syncthreads();
        #pragma unroll
        for (int i = 0; i < 4; ++i) {
            int c = i * 256 + tid;
            int row = c >> 3, colo = (c & 7) << 3;
            const float* s = x + (brow + row) * K_DIM + k0 + colo;
            float4 a = *(const float4*)s;
            float4 b = *(const float4*)(s + 4);
            ushort8 o;
            o[0] = f2bf(a.x); o[1] = f2bf(a.y); o[2] = f2bf(a.z); o[3] = f2bf(a.w);
            o[4] = f2bf(b.x); o[5] = f2bf(b.y); o[6] = f2bf(b.z); o[7] = f2bf(b.w);
            *(ushort8*)(&As[c << 3]) = o;
        }
        #pragma unroll
        for (int i = 0; i < 4; ++i) {
            int c = i * 256 + tid;
            int row = c >> 3, colo = (c & 7) << 3;
            const float* s = wsrc + ((bcol + row) & 1023) * 1024 + ((k0 + colo) & 1023);
            float4 a = *(const float4*)s;
            float4 b = *(const float4*)(s + 4);
            ushort8 o;
            o[0] = f2bf_sgn(a.x, sg); o[1] = f2bf_sgn(a.y, sg);
            o[2] = f2bf_sgn(a.z, sg); o[3] = f2bf_sgn(a.w, sg);
            o[4] = f2bf_sgn(b.x, sg); o[5] = f2bf_sgn(b.y, sg);
            o[6] = f2bf_sgn(b.z, sg); o[7] = f2bf_sgn(b.w, sg);
            *(ushort8*)(&Bs[c << 3]) = o;
        }
        __syncthreads();

        #pragma unroll
        for (int ks = 0; ks < 2; ++ks) {
            bf16x8 af[4], bfr[4];
            #pragma unroll
            for (int m = 0; m < 4; ++m)
                af[m] = *(const bf16x8*)(&As[(wm + m * 16 + fr) * BK + ks * 32 + fk]);
            #pragma unroll
            for (int n = 0; n < 4; ++n)
                bfr[n] = *(const bf16x8*)(&Bs[(wn + n * 16 + fr) * BK + ks * 32 + fk]);
            #pragma unroll
            for (int m = 0; m < 4; ++m)
                #pragma unroll
                for (int n = 0; n < 4; ++n)
                    acc[m][n] = __builtin_amdgcn_mfma_f32_16x16x32_bf16(
                        af[m], bfr[n], acc[m][n], 0, 0, 0);
        }
    }

    int cr = (lane >> 4) << 2;
    int cc = lane & 15;
    #pragma unroll
    for (int n = 0; n < 4; ++n) {
        int col = bcol + wn + n * 16 + cc;
        float bv = bias[col];
        #pragma unroll
        for (int m = 0; m < 4; ++m) {
            int r0 = brow + wm + m * 16 + cr;
            #pragma unroll
            for (int r = 0; r < 4; ++r)
                out[(r0 + r) * N_DIM + col] = acc[m][n][r] + bv;
        }
    }
}

extern "C" void kernel_launch(void* const* d_in, const int* in_sizes, int n_in,
                              void* d_out, int out_size, void* d_ws, size_t ws_size,
                              hipStream_t stream) {
    const float* x    = (const float*)d_in[0];
    const float* Wr   = (const float*)d_in[1];
    const float* Wi   = (const float*)d_in[2];
    const float* Wj   = (const float*)d_in[3];
    const float* Wk   = (const float*)d_in[4];
    const float* bias = (const float*)d_in[5];
    float* out = (float*)d_out;

    const size_t xb_bytes = (size_t)M_DIM * K_DIM * 2;  // 64 MiB
    const size_t wb_bytes = (size_t)N_DIM * K_DIM * 2;  // 32 MiB
    const int n_blocks = (M_DIM / BM) * (N_DIM / BN);   // 2048

    if (ws_size >= xb_bytes + wb_bytes) {
        unsigned short* xb = (unsigned short*)d_ws;
        unsigned short* wb = (unsigned short*)((char*)d_ws + xb_bytes);
        cvt_x_kernel<<<(M_DIM * K_DIM) / 2048, 256, 0, stream>>>(x, xb);
        prep_w_kernel<<<N_DIM * 2, 256, 0, stream>>>(Wr, Wi, Wj, Wk, wb);
        qgemm_bf16<<<n_blocks, 256, 0, stream>>>(xb, wb, bias, out);
    } else {
        qgemm_fb<<<n_blocks, 256, 0, stream>>>(x, Wr, Wi, Wj, Wk, bias, out);
    }
}

// Round 4
// 275.338 us; speedup vs baseline: 1.5542x; 1.5542x over previous
//
#include <hip/hip_runtime.h>
#include <hip/hip_bf16.h>

// QuaternionLinear = one 8192x4096x4096 GEMM vs Hamilton-assembled W.
// Round 4: 256^2 8-phase template (T2 swizzle + T3/T4 counted-vmcnt pipeline
// + T5 setprio). Prep kernels convert x and Hamilton-assemble W to bf16 in ws.

#define M_DIM 8192
#define N_DIM 4096
#define K_DIM 4096
#define BK 64
#define NT (K_DIM / BK)   // 64 K-tiles

typedef __attribute__((ext_vector_type(8))) short bf16x8;
typedef __attribute__((ext_vector_type(4))) float f32x4;
typedef __attribute__((ext_vector_type(8))) unsigned short ushort8;

static __device__ __forceinline__ unsigned short f2bf(float f) {
    unsigned int u = __float_as_uint(f);
    return (unsigned short)((u + 0x7fffu + ((u >> 16) & 1u)) >> 16);
}
static __device__ __forceinline__ unsigned short f2bf_sgn(float f, unsigned int sg) {
    unsigned int u = __float_as_uint(f) ^ sg;
    return (unsigned short)((u + 0x7fffu + ((u >> 16) & 1u)) >> 16);
}

// ---------------- prep: x (fp32) -> xb (bf16) ----------------
__global__ __launch_bounds__(256) void cvt_x_kernel(const float* __restrict__ x,
                                                    unsigned short* __restrict__ xb) {
    int i = (blockIdx.x * 256 + threadIdx.x) * 8;
    float4 a = *(const float4*)(x + i);
    float4 b = *(const float4*)(x + i + 4);
    ushort8 o;
    o[0] = f2bf(a.x); o[1] = f2bf(a.y); o[2] = f2bf(a.z); o[3] = f2bf(a.w);
    o[4] = f2bf(b.x); o[5] = f2bf(b.y); o[6] = f2bf(b.z); o[7] = f2bf(b.w);
    *(ushort8*)(xb + i) = o;
}

// ---------------- prep: assemble Hamilton W (bf16) ----------------
// Wb[o][i] = sign(p,q) * Wc[p^q][o&1023][i&1023], p=o>>10, q=i>>10,
// neg iff bit (p*4+q) of 0x428E.
__global__ __launch_bounds__(256) void prep_w_kernel(const float* __restrict__ Wr,
    const float* __restrict__ Wi, const float* __restrict__ Wj,
    const float* __restrict__ Wk, unsigned short* __restrict__ wb) {
    int row = blockIdx.x >> 1;
    int col = ((blockIdx.x & 1) * 256 + threadIdx.x) * 8;
    int p = row >> 10, q = col >> 10;
    int ci = p ^ q;
    const float* src = (ci == 0) ? Wr : (ci == 1) ? Wi : (ci == 2) ? Wj : Wk;
    unsigned int sg = ((0x428Eu >> (p * 4 + q)) & 1u) << 31;
    int so = (row & 1023) * 1024 + (col & 1023);
    float4 a = *(const float4*)(src + so);
    float4 b = *(const float4*)(src + so + 4);
    ushort8 o;
    o[0] = f2bf_sgn(a.x, sg); o[1] = f2bf_sgn(a.y, sg);
    o[2] = f2bf_sgn(a.z, sg); o[3] = f2bf_sgn(a.w, sg);
    o[4] = f2bf_sgn(b.x, sg); o[5] = f2bf_sgn(b.y, sg);
    o[6] = f2bf_sgn(b.z, sg); o[7] = f2bf_sgn(b.w, sg);
    *(ushort8*)(wb + row * 4096 + col) = o;
}

// ---------------- main GEMM: 256^2 8-phase ----------------
#define GLD16(gp, lp) __builtin_amdgcn_global_load_lds( \
    (const __attribute__((address_space(1))) void*)(gp), \
    (__attribute__((address_space(3))) void*)(lp), 16, 0, 0)

#define BAR()   do { __builtin_amdgcn_s_barrier(); __builtin_amdgcn_sched_barrier(0); } while (0)
#define LGKM0() do { asm volatile("s_waitcnt lgkmcnt(0)" ::: "memory"); \
                     __builtin_amdgcn_sched_barrier(0); } while (0)
#define VM(n)   do { asm volatile("s_waitcnt vmcnt(" #n ")" ::: "memory"); \
                     __builtin_amdgcn_sched_barrier(0); } while (0)

static __device__ __forceinline__ f32x4 MF(bf16x8 a, bf16x8 b, f32x4 c) {
    return __builtin_amdgcn_mfma_f32_16x16x32_bf16(a, b, c, 0, 0, 0);
}

__global__ __launch_bounds__(512, 2) void qgemm_bf16(
    const unsigned short* __restrict__ A, const unsigned short* __restrict__ B,
    const float* __restrict__ bias, float* __restrict__ out)
{
    // [buf][A=0/B=1][half][128 rows][64 shorts] = 128 KiB.
    // Content swizzle: linear slot s at row r holds logical k-slot s^(r&7)
    // (16B slots). Applied on the global SOURCE at stage time and on the
    // ds_read address (both-sides, rule #21).
    __shared__ __align__(16) unsigned short Lsh[2][2][2][128 * 64];

    int bid = blockIdx.x;
    int cpx = gridDim.x >> 3;                 // 512/8 = 64, 512%8==0 bijective
    int wg  = (bid & 7) * cpx + (bid >> 3);
    int brow = (wg >> 4) * 256;               // 32 M-tiles
    int bcol = (wg & 15) * 256;               // 16 N-tiles

    int tid   = threadIdx.x;
    int lane  = tid & 63;
    int wid   = tid >> 6;
    int hA    = wid >> 2;                     // wave's A half (128 rows)
    int nb    = wid & 3;                      // wave's 64-col B band
    int hB    = nb >> 1;
    int rB0   = (nb & 1) << 6;
    int fr    = lane & 15;
    int fslot = lane >> 4;                    // 0..3

    const unsigned short* Ag = A + (size_t)brow * K_DIM;
    const unsigned short* Bg = B + (size_t)bcol * K_DIM;

    f32x4 acc[8][4] = {};

    auto stage = [&](int buf, int ab, int half, int t) {
        const unsigned short* g = (ab ? Bg : Ag) + (size_t)(half << 7) * K_DIM + t * BK;
        unsigned short* l = &Lsh[buf][ab][half][0];
        #pragma unroll
        for (int i = 0; i < 2; ++i) {
            int c = i * 512 + tid;            // 16B chunk: row=c>>3, slot=c&7
            int r = c >> 3, s = c & 7;
            // linear LDS dest (lane-contiguous), pre-swizzled global source
            GLD16(g + (size_t)r * K_DIM + ((s ^ (r & 7)) << 3), l + (c << 3));
        }
    };
    auto rdA = [&](int buf, int mi, int ks) -> bf16x8 {
        int r = mi * 16 + fr;
        int slot = (ks * 4 + fslot) ^ (r & 7);
        return *(const bf16x8*)((const char*)&Lsh[buf][0][hA][0] + r * 128 + (slot << 4));
    };
    auto rdB = [&](int buf, int ni, int ks) -> bf16x8 {
        int r = rB0 + ni * 16 + fr;
        int slot = (ks * 4 + fslot) ^ (r & 7);
        return *(const bf16x8*)((const char*)&Lsh[buf][1][hB][0] + r * 128 + (slot << 4));
    };

    // Prologue: tile0 A+B into buf0, tile1 B into buf1. vmcnt(4) leaves the
    // 4 tile1-B loads in flight (they land before tile1.q0, enforced by the
    // vmcnt(4) at end of tile0).
    stage(0, 0, 0, 0); stage(0, 0, 1, 0); stage(0, 1, 0, 0); stage(0, 1, 1, 0);
    stage(1, 1, 0, 1); stage(1, 1, 1, 1);
    VM(4); BAR();

    for (int t = 0; t < NT; ++t) {
        int buf = t & 1;
        bf16x8 bfrag[4][2];

        // ---- phase 0: read ALL B frags + A m0,m1; stage A-half0(t+1) ----
        #pragma unroll
        for (int ni = 0; ni < 4; ++ni) {
            bfrag[ni][0] = rdB(buf, ni, 0);
            bfrag[ni][1] = rdB(buf, ni, 1);
        }
        {
            bf16x8 x0 = rdA(buf, 0, 0), x1 = rdA(buf, 0, 1);
            bf16x8 x2 = rdA(buf, 1, 0), x3 = rdA(buf, 1, 1);
            if (t + 1 < NT) stage(buf ^ 1, 0, 0, t + 1);
            BAR(); LGKM0();
            __builtin_amdgcn_s_setprio(1);
            #pragma unroll
            for (int ni = 0; ni < 4; ++ni) {
                acc[0][ni] = MF(x0, bfrag[ni][0], acc[0][ni]);
                acc[0][ni] = MF(x1, bfrag[ni][1], acc[0][ni]);
                acc[1][ni] = MF(x2, bfrag[ni][0], acc[1][ni]);
                acc[1][ni] = MF(x3, bfrag[ni][1], acc[1][ni]);
            }
            __builtin_amdgcn_s_setprio(0);
            BAR();
        }
        // ---- phase 1: A m2,m3; stage A-half1(t+1) ----
        {
            bf16x8 x0 = rdA(buf, 2, 0), x1 = rdA(buf, 2, 1);
            bf16x8 x2 = rdA(buf, 3, 0), x3 = rdA(buf, 3, 1);
            if (t + 1 < NT) stage(buf ^ 1, 0, 1, t + 1);
            BAR(); LGKM0();
            __builtin_amdgcn_s_setprio(1);
            #pragma unroll
            for (int ni = 0; ni < 4; ++ni) {
                acc[2][ni] = MF(x0, bfrag[ni][0], acc[2][ni]);
                acc[2][ni] = MF(x1, bfrag[ni][1], acc[2][ni]);
                acc[3][ni] = MF(x2, bfrag[ni][0], acc[3][ni]);
                acc[3][ni] = MF(x3, bfrag[ni][1], acc[3][ni]);
            }
            __builtin_amdgcn_s_setprio(0);
            BAR();
        }
        // ---- phase 2: A m4,m5; stage B-half0(t+2) into SAME buf (B already
        //      consumed into registers in phase 0) ----
        {
            bf16x8 x0 = rdA(buf, 4, 0), x1 = rdA(buf, 4, 1);
            bf16x8 x2 = rdA(buf, 5, 0), x3 = rdA(buf, 5, 1);
            if (t + 2 < NT) stage(buf, 1, 0, t + 2);
            BAR(); LGKM0();
            __builtin_amdgcn_s_setprio(1);
            #pragma unroll
            for (int ni = 0; ni < 4; ++ni) {
                acc[4][ni] = MF(x0, bfrag[ni][0], acc[4][ni]);
                acc[4][ni] = MF(x1, bfrag[ni][1], acc[4][ni]);
                acc[5][ni] = MF(x2, bfrag[ni][0], acc[5][ni]);
                acc[5][ni] = MF(x3, bfrag[ni][1], acc[5][ni]);
            }
            __builtin_amdgcn_s_setprio(0);
            BAR();
        }
        // ---- phase 3: A m6,m7; stage B-half1(t+2); counted vmcnt ----
        {
            bf16x8 x0 = rdA(buf, 6, 0), x1 = rdA(buf, 6, 1);
            bf16x8 x2 = rdA(buf, 7, 0), x3 = rdA(buf, 7, 1);
            if (t + 2 < NT) stage(buf, 1, 1, t + 2);
            BAR(); LGKM0();
            __builtin_amdgcn_s_setprio(1);
            #pragma unroll
            for (int ni = 0; ni < 4; ++ni) {
                acc[6][ni] = MF(x0, bfrag[ni][0], acc[6][ni]);
                acc[6][ni] = MF(x1, bfrag[ni][1], acc[6][ni]);
                acc[7][ni] = MF(x2, bfrag[ni][0], acc[7][ni]);
                acc[7][ni] = MF(x3, bfrag[ni][1], acc[7][ni]);
            }
            __builtin_amdgcn_s_setprio(0);
            // Retire A(t+1) + B(t+1); leave the 4 newest (B(t+2)) in flight.
            if (t < NT - 2) { VM(4); } else { VM(0); }
            BAR();
        }
    }

    // epilogue: C/D layout col=lane&15, row=(lane>>4)*4+reg
    int cr = (lane >> 4) << 2;
    int cc = lane & 15;
    #pragma unroll
    for (int ni = 0; ni < 4; ++ni) {
        int col = bcol + nb * 64 + ni * 16 + cc;
        float bv = bias[col];
        #pragma unroll
        for (int mi = 0; mi < 8; ++mi) {
            int r0 = brow + hA * 128 + mi * 16 + cr;
            #pragma unroll
            for (int r = 0; r < 4; ++r)
                out[(size_t)(r0 + r) * N_DIM + col] = acc[mi][ni][r] + bv;
        }
    }
}

// ---------------- fallback: reg-staged, no workspace (round-3, known-good) --
#define FBM 128
#define FBN 128
#define FBK 64
__global__ __launch_bounds__(256) void qgemm_fb(const float* __restrict__ x,
    const float* __restrict__ Wr, const float* __restrict__ Wi,
    const float* __restrict__ Wj, const float* __restrict__ Wk,
    const float* __restrict__ bias, float* __restrict__ out)
{
    __shared__ unsigned short As[FBM * FBK];
    __shared__ unsigned short Bs[FBN * FBK];

    int bid = blockIdx.x;
    int cpx = gridDim.x >> 3;
    int wg = (bid & 7) * cpx + (bid >> 3);
    int brow = (wg >> 5) * FBM;
    int bcol = (wg & 31) * FBN;

    int tid = threadIdx.x;
    int lane = tid & 63;
    int wv = tid >> 6;
    int wm = (wv >> 1) << 6;
    int wn = (wv & 1) << 6;
    int fr = lane & 15;
    int fk = (lane >> 4) << 3;

    int p = bcol >> 10;
    f32x4 acc[4][4] = {};

    for (int kt = 0; kt < K_DIM / FBK; ++kt) {
        int k0 = kt * FBK;
        int q = k0 >> 10;
        int ci = p ^ q;
        const float* wsrc = (ci == 0) ? Wr : (ci == 1) ? Wi : (ci == 2) ? Wj : Wk;
        unsigned int sg = ((0x428Eu >> (p * 4 + q)) & 1u) << 31;

        __syncthreads();
        #pragma unroll
        for (int i = 0; i < 4; ++i) {
            int c = i * 256 + tid;
            int row = c >> 3, colo = (c & 7) << 3;
            const float* s = x + (size_t)(brow + row) * K_DIM + k0 + colo;
            float4 a = *(const float4*)s;
            float4 b = *(const float4*)(s + 4);
            ushort8 o;
            o[0] = f2bf(a.x); o[1] = f2bf(a.y); o[2] = f2bf(a.z); o[3] = f2bf(a.w);
            o[4] = f2bf(b.x); o[5] = f2bf(b.y); o[6] = f2bf(b.z); o[7] = f2bf(b.w);
            *(ushort8*)(&As[c << 3]) = o;
        }
        #pragma unroll
        for (int i = 0; i < 4; ++i) {
            int c = i * 256 + tid;
            int row = c >> 3, colo = (c & 7) << 3;
            const float* s = wsrc + ((bcol + row) & 1023) * 1024 + ((k0 + colo) & 1023);
            float4 a = *(const float4*)s;
            float4 b = *(const float4*)(s + 4);
            ushort8 o;
            o[0] = f2bf_sgn(a.x, sg); o[1] = f2bf_sgn(a.y, sg);
            o[2] = f2bf_sgn(a.z, sg); o[3] = f2bf_sgn(a.w, sg);
            o[4] = f2bf_sgn(b.x, sg); o[5] = f2bf_sgn(b.y, sg);
            o[6] = f2bf_sgn(b.z, sg); o[7] = f2bf_sgn(b.w, sg);
            *(ushort8*)(&Bs[c << 3]) = o;
        }
        __syncthreads();

        #pragma unroll
        for (int ks = 0; ks < 2; ++ks) {
            bf16x8 af[4], bfr[4];
            #pragma unroll
            for (int m = 0; m < 4; ++m)
                af[m] = *(const bf16x8*)(&As[(wm + m * 16 + fr) * FBK + ks * 32 + fk]);
            #pragma unroll
            for (int n = 0; n < 4; ++n)
                bfr[n] = *(const bf16x8*)(&Bs[(wn + n * 16 + fr) * FBK + ks * 32 + fk]);
            #pragma unroll
            for (int m = 0; m < 4; ++m)
                #pragma unroll
                for (int n = 0; n < 4; ++n)
                    acc[m][n] = __builtin_amdgcn_mfma_f32_16x16x32_bf16(
                        af[m], bfr[n], acc[m][n], 0, 0, 0);
        }
    }

    int cr = (lane >> 4) << 2;
    int cc = lane & 15;
    #pragma unroll
    for (int n = 0; n < 4; ++n) {
        int col = bcol + wn + n * 16 + cc;
        float bv = bias[col];
        #pragma unroll
        for (int m = 0; m < 4; ++m) {
            int r0 = brow + wm + m * 16 + cr;
            #pragma unroll
            for (int r = 0; r < 4; ++r)
                out[(size_t)(r0 + r) * N_DIM + col] = acc[m][n][r] + bv;
        }
    }
}

extern "C" void kernel_launch(void* const* d_in, const int* in_sizes, int n_in,
                              void* d_out, int out_size, void* d_ws, size_t ws_size,
                              hipStream_t stream) {
    const float* x    = (const float*)d_in[0];
    const float* Wr   = (const float*)d_in[1];
    const float* Wi   = (const float*)d_in[2];
    const float* Wj   = (const float*)d_in[3];
    const float* Wk   = (const float*)d_in[4];
    const float* bias = (const float*)d_in[5];
    float* out = (float*)d_out;

    const size_t xb_bytes = (size_t)M_DIM * K_DIM * 2;  // 64 MiB
    const size_t wb_bytes = (size_t)N_DIM * K_DIM * 2;  // 32 MiB

    if (ws_size >= xb_bytes + wb_bytes) {
        unsigned short* xb = (unsigned short*)d_ws;
        unsigned short* wb = (unsigned short*)((char*)d_ws + xb_bytes);
        cvt_x_kernel<<<(M_DIM * K_DIM) / 2048, 256, 0, stream>>>(x, xb);
        prep_w_kernel<<<N_DIM * 2, 256, 0, stream>>>(Wr, Wi, Wj, Wk, wb);
        const int n_blocks = (M_DIM / 256) * (N_DIM / 256);  // 512
        qgemm_bf16<<<n_blocks, 512, 0, stream>>>(xb, wb, bias, out);
    } else {
        const int n_blocks = (M_DIM / FBM) * (N_DIM / FBN);  // 2048
        qgemm_fb<<<n_blocks, 256, 0, stream>>>(x, Wr, Wi, Wj, Wk, bias, out);
    }
}

// Round 5
// 273.985 us; speedup vs baseline: 1.5619x; 1.0049x over previous
//
#include <hip/hip_runtime.h>
#include <hip/hip_bf16.h>

// QuaternionLinear = one 8192x4096x4096 GEMM vs Hamilton-assembled W.
// Round 5: 256^2 8-phase (T2 swizzle + T3/T4 counted-vmcnt + T5 setprio),
// UNPINNED scheduling (no sched_barrier(0) — m141 lesson; compiler derives
// lgkmcnt for ds_read->MFMA deps itself). Deeper A-prefetch slack (both A
// halves issued in phase 0). Nontemporal out-stores to keep xb/wb L3-resident.

#define M_DIM 8192
#define N_DIM 4096
#define K_DIM 4096
#define BK 64
#define NT (K_DIM / BK)   // 64 K-tiles

typedef __attribute__((ext_vector_type(8))) short bf16x8;
typedef __attribute__((ext_vector_type(4))) float f32x4;
typedef __attribute__((ext_vector_type(8))) unsigned short ushort8;

static __device__ __forceinline__ unsigned short f2bf(float f) {
    unsigned int u = __float_as_uint(f);
    return (unsigned short)((u + 0x7fffu + ((u >> 16) & 1u)) >> 16);
}
static __device__ __forceinline__ unsigned short f2bf_sgn(float f, unsigned int sg) {
    unsigned int u = __float_as_uint(f) ^ sg;
    return (unsigned short)((u + 0x7fffu + ((u >> 16) & 1u)) >> 16);
}

// ---------------- prep: x (fp32) -> xb (bf16) ----------------
__global__ __launch_bounds__(256) void cvt_x_kernel(const float* __restrict__ x,
                                                    unsigned short* __restrict__ xb) {
    int i = (blockIdx.x * 256 + threadIdx.x) * 8;
    f32x4 a = __builtin_nontemporal_load((const f32x4*)(x + i));      // read-once
    f32x4 b = __builtin_nontemporal_load((const f32x4*)(x + i + 4));
    ushort8 o;
    o[0] = f2bf(a[0]); o[1] = f2bf(a[1]); o[2] = f2bf(a[2]); o[3] = f2bf(a[3]);
    o[4] = f2bf(b[0]); o[5] = f2bf(b[1]); o[6] = f2bf(b[2]); o[7] = f2bf(b[3]);
    *(ushort8*)(xb + i) = o;   // xb is re-read 16x -> keep cacheable
}

// ---------------- prep: assemble Hamilton W (bf16) ----------------
// Wb[o][i] = sign(p,q) * Wc[p^q][o&1023][i&1023], p=o>>10, q=i>>10,
// neg iff bit (p*4+q) of 0x428E.
__global__ __launch_bounds__(256) void prep_w_kernel(const float* __restrict__ Wr,
    const float* __restrict__ Wi, const float* __restrict__ Wj,
    const float* __restrict__ Wk, unsigned short* __restrict__ wb) {
    int row = blockIdx.x >> 1;
    int col = ((blockIdx.x & 1) * 256 + threadIdx.x) * 8;
    int p = row >> 10, q = col >> 10;
    int ci = p ^ q;
    const float* src = (ci == 0) ? Wr : (ci == 1) ? Wi : (ci == 2) ? Wj : Wk;
    unsigned int sg = ((0x428Eu >> (p * 4 + q)) & 1u) << 31;
    int so = (row & 1023) * 1024 + (col & 1023);
    f32x4 a = *(const f32x4*)(src + so);        // each W quadrant read 4x -> cacheable
    f32x4 b = *(const f32x4*)(src + so + 4);
    ushort8 o;
    o[0] = f2bf_sgn(a[0], sg); o[1] = f2bf_sgn(a[1], sg);
    o[2] = f2bf_sgn(a[2], sg); o[3] = f2bf_sgn(a[3], sg);
    o[4] = f2bf_sgn(b[0], sg); o[5] = f2bf_sgn(b[1], sg);
    o[6] = f2bf_sgn(b[2], sg); o[7] = f2bf_sgn(b[3], sg);
    *(ushort8*)(wb + row * 4096 + col) = o;
}

// ---------------- main GEMM: 256^2 8-phase ----------------
#define GLD16(gp, lp) __builtin_amdgcn_global_load_lds( \
    (const __attribute__((address_space(1))) void*)(gp), \
    (__attribute__((address_space(3))) void*)(lp), 16, 0, 0)

// s_barrier bracketed by zero-cost compiler memory fences: LDS reads and
// global_load_lds cannot migrate across a barrier (correctness of buffer
// reuse) but VALU/MFMA scheduling stays free (no sched_barrier pinning).
#define BAR() do { asm volatile("" ::: "memory"); \
                   __builtin_amdgcn_s_barrier(); \
                   asm volatile("" ::: "memory"); } while (0)
// Counted vmcnt: the one wait the compiler cannot derive (cross-wave
// global_load_lds -> ds_read dependency). Memory clobber orders it.
#define VM(n) asm volatile("s_waitcnt vmcnt(" #n ")" ::: "memory")

static __device__ __forceinline__ f32x4 MF(bf16x8 a, bf16x8 b, f32x4 c) {
    return __builtin_amdgcn_mfma_f32_16x16x32_bf16(a, b, c, 0, 0, 0);
}

__global__ __launch_bounds__(512, 2) void qgemm_bf16(
    const unsigned short* __restrict__ A, const unsigned short* __restrict__ B,
    const float* __restrict__ bias, float* __restrict__ out)
{
    // [buf][A=0/B=1][half][128 rows][64 shorts] = 128 KiB.
    // Content swizzle: linear slot s at row r holds logical k-slot s^(r&7)
    // (16B slots): pre-swizzled global SOURCE at stage time + swizzled
    // ds_read address (both-sides, rule #21).
    __shared__ __align__(16) unsigned short Lsh[2][2][2][128 * 64];

    int bid = blockIdx.x;
    int cpx = gridDim.x >> 3;                 // 512/8 = 64, 512%8==0 bijective
    int wg  = (bid & 7) * cpx + (bid >> 3);
    int brow = (wg >> 4) * 256;               // 32 M-tiles
    int bcol = (wg & 15) * 256;               // 16 N-tiles

    int tid   = threadIdx.x;
    int lane  = tid & 63;
    int wid   = tid >> 6;
    int hA    = wid >> 2;                     // wave's A half (128 rows)
    int nb    = wid & 3;                      // wave's 64-col B band
    int hB    = nb >> 1;
    int rB0   = (nb & 1) << 6;
    int fr    = lane & 15;
    int fslot = lane >> 4;                    // 0..3

    const unsigned short* Ag = A + (size_t)brow * K_DIM;
    const unsigned short* Bg = B + (size_t)bcol * K_DIM;

    f32x4 acc[8][4] = {};

    auto stage = [&](int buf, int ab, int half, int t) {
        const unsigned short* g = (ab ? Bg : Ag) + (size_t)(half << 7) * K_DIM + t * BK;
        unsigned short* l = &Lsh[buf][ab][half][0];
        #pragma unroll
        for (int i = 0; i < 2; ++i) {
            int c = i * 512 + tid;            // 16B chunk: row=c>>3, slot=c&7
            int r = c >> 3, s = c & 7;
            GLD16(g + (size_t)r * K_DIM + ((s ^ (r & 7)) << 3), l + (c << 3));
        }
    };
    auto rdA = [&](int buf, int mi, int ks) -> bf16x8 {
        int r = mi * 16 + fr;
        int slot = (ks * 4 + fslot) ^ (r & 7);
        return *(const bf16x8*)((const char*)&Lsh[buf][0][hA][0] + r * 128 + (slot << 4));
    };
    auto rdB = [&](int buf, int ni, int ks) -> bf16x8 {
        int r = rB0 + ni * 16 + fr;
        int slot = (ks * 4 + fslot) ^ (r & 7);
        return *(const bf16x8*)((const char*)&Lsh[buf][1][hB][0] + r * 128 + (slot << 4));
    };

    // Prologue: tile0 A+B into buf0 (8 loads), tile1 B into buf1 (4 loads).
    // VM(4) retires tile0, leaves tile1-B in flight.
    stage(0, 0, 0, 0); stage(0, 0, 1, 0); stage(0, 1, 0, 0); stage(0, 1, 1, 0);
    stage(1, 1, 0, 1); stage(1, 1, 1, 1);
    VM(4); BAR();

    for (int t = 0; t < NT; ++t) {
        int buf = t & 1;
        bf16x8 bfrag[4][2];

        // ---- phase 0: all B frags + A m0,m1; stage BOTH A(t+1) halves ----
        #pragma unroll
        for (int ni = 0; ni < 4; ++ni) {
            bfrag[ni][0] = rdB(buf, ni, 0);
            bfrag[ni][1] = rdB(buf, ni, 1);
        }
        {
            bf16x8 x0 = rdA(buf, 0, 0), x1 = rdA(buf, 0, 1);
            bf16x8 x2 = rdA(buf, 1, 0), x3 = rdA(buf, 1, 1);
            if (t + 1 < NT) { stage(buf ^ 1, 0, 0, t + 1); stage(buf ^ 1, 0, 1, t + 1); }
            BAR();
            __builtin_amdgcn_s_setprio(1);
            #pragma unroll
            for (int ni = 0; ni < 4; ++ni) {
                acc[0][ni] = MF(x0, bfrag[ni][0], acc[0][ni]);
                acc[0][ni] = MF(x1, bfrag[ni][1], acc[0][ni]);
                acc[1][ni] = MF(x2, bfrag[ni][0], acc[1][ni]);
                acc[1][ni] = MF(x3, bfrag[ni][1], acc[1][ni]);
            }
            __builtin_amdgcn_s_setprio(0);
            BAR();
        }
        // ---- phase 1: A m2,m3; stage B-half0(t+2) into SAME buf (B-region
        //      fully consumed into registers in phase 0) ----
        {
            bf16x8 x0 = rdA(buf, 2, 0), x1 = rdA(buf, 2, 1);
            bf16x8 x2 = rdA(buf, 3, 0), x3 = rdA(buf, 3, 1);
            if (t + 2 < NT) stage(buf, 1, 0, t + 2);
            BAR();
            __builtin_amdgcn_s_setprio(1);
            #pragma unroll
            for (int ni = 0; ni < 4; ++ni) {
                acc[2][ni] = MF(x0, bfrag[ni][0], acc[2][ni]);
                acc[2][ni] = MF(x1, bfrag[ni][1], acc[2][ni]);
                acc[3][ni] = MF(x2, bfrag[ni][0], acc[3][ni]);
                acc[3][ni] = MF(x3, bfrag[ni][1], acc[3][ni]);
            }
            __builtin_amdgcn_s_setprio(0);
            BAR();
        }
        // ---- phase 2: A m4,m5; stage B-half1(t+2) ----
        {
            bf16x8 x0 = rdA(buf, 4, 0), x1 = rdA(buf, 4, 1);
            bf16x8 x2 = rdA(buf, 5, 0), x3 = rdA(buf, 5, 1);
            if (t + 2 < NT) stage(buf, 1, 1, t + 2);
            BAR();
            __builtin_amdgcn_s_setprio(1);
            #pragma unroll
            for (int ni = 0; ni < 4; ++ni) {
                acc[4][ni] = MF(x0, bfrag[ni][0], acc[4][ni]);
                acc[4][ni] = MF(x1, bfrag[ni][1], acc[4][ni]);
                acc[5][ni] = MF(x2, bfrag[ni][0], acc[5][ni]);
                acc[5][ni] = MF(x3, bfrag[ni][1], acc[5][ni]);
            }
            __builtin_amdgcn_s_setprio(0);
            BAR();
        }
        // ---- phase 3: A m6,m7; no stage; counted vmcnt at tile boundary ----
        {
            bf16x8 x0 = rdA(buf, 6, 0), x1 = rdA(buf, 6, 1);
            bf16x8 x2 = rdA(buf, 7, 0), x3 = rdA(buf, 7, 1);
            BAR();
            __builtin_amdgcn_s_setprio(1);
            #pragma unroll
            for (int ni = 0; ni < 4; ++ni) {
                acc[6][ni] = MF(x0, bfrag[ni][0], acc[6][ni]);
                acc[6][ni] = MF(x1, bfrag[ni][1], acc[6][ni]);
                acc[7][ni] = MF(x2, bfrag[ni][0], acc[7][ni]);
                acc[7][ni] = MF(x3, bfrag[ni][1], acc[7][ni]);
            }
            __builtin_amdgcn_s_setprio(0);
            // Retire A(t+1)+B(t+1); leave the 4 newest (B(t+2)) in flight.
            if (t < NT - 2) { VM(4); } else { VM(0); }
            BAR();
        }
    }

    // epilogue: C/D layout col=lane&15, row=(lane>>4)*4+reg.
    // Nontemporal stores: out (128 MiB, write-once) must not evict xb/wb
    // operand panels from L2/L3.
    int cr = (lane >> 4) << 2;
    int cc = lane & 15;
    #pragma unroll
    for (int ni = 0; ni < 4; ++ni) {
        int col = bcol + nb * 64 + ni * 16 + cc;
        float bv = bias[col];
        #pragma unroll
        for (int mi = 0; mi < 8; ++mi) {
            int r0 = brow + hA * 128 + mi * 16 + cr;
            #pragma unroll
            for (int r = 0; r < 4; ++r)
                __builtin_nontemporal_store(acc[mi][ni][r] + bv,
                                            &out[(size_t)(r0 + r) * N_DIM + col]);
        }
    }
}

// ---------------- fallback: reg-staged, no workspace (round-3, known-good) --
#define FBM 128
#define FBN 128
#define FBK 64
__global__ __launch_bounds__(256) void qgemm_fb(const float* __restrict__ x,
    const float* __restrict__ Wr, const float* __restrict__ Wi,
    const float* __restrict__ Wj, const float* __restrict__ Wk,
    const float* __restrict__ bias, float* __restrict__ out)
{
    __shared__ unsigned short As[FBM * FBK];
    __shared__ unsigned short Bs[FBN * FBK];

    int bid = blockIdx.x;
    int cpx = gridDim.x >> 3;
    int wg = (bid & 7) * cpx + (bid >> 3);
    int brow = (wg >> 5) * FBM;
    int bcol = (wg & 31) * FBN;

    int tid = threadIdx.x;
    int lane = tid & 63;
    int wv = tid >> 6;
    int wm = (wv >> 1) << 6;
    int wn = (wv & 1) << 6;
    int fr = lane & 15;
    int fk = (lane >> 4) << 3;

    int p = bcol >> 10;
    f32x4 acc[4][4] = {};

    for (int kt = 0; kt < K_DIM / FBK; ++kt) {
        int k0 = kt * FBK;
        int q = k0 >> 10;
        int ci = p ^ q;
        const float* wsrc = (ci == 0) ? Wr : (ci == 1) ? Wi : (ci == 2) ? Wj : Wk;
        unsigned int sg = ((0x428Eu >> (p * 4 + q)) & 1u) << 31;

        __syncthreads();
        #pragma unroll
        for (int i = 0; i < 4; ++i) {
            int c = i * 256 + tid;
            int row = c >> 3, colo = (c & 7) << 3;
            const float* s = x + (size_t)(brow + row) * K_DIM + k0 + colo;
            float4 a = *(const float4*)s;
            float4 b = *(const float4*)(s + 4);
            ushort8 o;
            o[0] = f2bf(a.x); o[1] = f2bf(a.y); o[2] = f2bf(a.z); o[3] = f2bf(a.w);
            o[4] = f2bf(b.x); o[5] = f2bf(b.y); o[6] = f2bf(b.z); o[7] = f2bf(b.w);
            *(ushort8*)(&As[c << 3]) = o;
        }
        #pragma unroll
        for (int i = 0; i < 4; ++i) {
            int c = i * 256 + tid;
            int row = c >> 3, colo = (c & 7) << 3;
            const float* s = wsrc + ((bcol + row) & 1023) * 1024 + ((k0 + colo) & 1023);
            float4 a = *(const float4*)s;
            float4 b = *(const float4*)(s + 4);
            ushort8 o;
            o[0] = f2bf_sgn(a.x, sg); o[1] = f2bf_sgn(a.y, sg);
            o[2] = f2bf_sgn(a.z, sg); o[3] = f2bf_sgn(a.w, sg);
            o[4] = f2bf_sgn(b.x, sg); o[5] = f2bf_sgn(b.y, sg);
            o[6] = f2bf_sgn(b.z, sg); o[7] = f2bf_sgn(b.w, sg);
            *(ushort8*)(&Bs[c << 3]) = o;
        }
        __syncthreads();

        #pragma unroll
        for (int ks = 0; ks < 2; ++ks) {
            bf16x8 af[4], bfr[4];
            #pragma unroll
            for (int m = 0; m < 4; ++m)
                af[m] = *(const bf16x8*)(&As[(wm + m * 16 + fr) * FBK + ks * 32 + fk]);
            #pragma unroll
            for (int n = 0; n < 4; ++n)
                bfr[n] = *(const bf16x8*)(&Bs[(wn + n * 16 + fr) * FBK + ks * 32 + fk]);
            #pragma unroll
            for (int m = 0; m < 4; ++m)
                #pragma unroll
                for (int n = 0; n < 4; ++n)
                    acc[m][n] = __builtin_amdgcn_mfma_f32_16x16x32_bf16(
                        af[m], bfr[n], acc[m][n], 0, 0, 0);
        }
    }

    int cr = (lane >> 4) << 2;
    int cc = lane & 15;
    #pragma unroll
    for (int n = 0; n < 4; ++n) {
        int col = bcol + wn + n * 16 + cc;
        float bv = bias[col];
        #pragma unroll
        for (int m = 0; m < 4; ++m) {
            int r0 = brow + wm + m * 16 + cr;
            #pragma unroll
            for (int r = 0; r < 4; ++r)
                out[(size_t)(r0 + r) * N_DIM + col] = acc[m][n][r] + bv;
        }
    }
}

extern "C" void kernel_launch(void* const* d_in, const int* in_sizes, int n_in,
                              void* d_out, int out_size, void* d_ws, size_t ws_size,
                              hipStream_t stream) {
    const float* x    = (const float*)d_in[0];
    const float* Wr   = (const float*)d_in[1];
    const float* Wi   = (const float*)d_in[2];
    const float* Wj   = (const float*)d_in[3];
    const float* Wk   = (const float*)d_in[4];
    const float* bias = (const float*)d_in[5];
    float* out = (float*)d_out;

    const size_t xb_bytes = (size_t)M_DIM * K_DIM * 2;  // 64 MiB
    const size_t wb_bytes = (size_t)N_DIM * K_DIM * 2;  // 32 MiB

    if (ws_size >= xb_bytes + wb_bytes) {
        unsigned short* xb = (unsigned short*)d_ws;
        unsigned short* wb = (unsigned short*)((char*)d_ws + xb_bytes);
        cvt_x_kernel<<<(M_DIM * K_DIM) / 2048, 256, 0, stream>>>(x, xb);
        prep_w_kernel<<<N_DIM * 2, 256, 0, stream>>>(Wr, Wi, Wj, Wk, wb);
        const int n_blocks = (M_DIM / 256) * (N_DIM / 256);  // 512
        qgemm_bf16<<<n_blocks, 512, 0, stream>>>(xb, wb, bias, out);
    } else {
        const int n_blocks = (M_DIM / FBM) * (N_DIM / FBN);  // 2048
        qgemm_fb<<<n_blocks, 256, 0, stream>>>(x, Wr, Wi, Wj, Wk, bias, out);
    }
}

// Round 7
// 273.822 us; speedup vs baseline: 1.5628x; 1.0006x over previous
//
#include <hip/hip_runtime.h>
#include <hip/hip_bf16.h>

// QuaternionLinear = one 8192x4096x4096 GEMM vs Hamilton-assembled W.
// Round 7 (= R6 with the compile error removed): merged-window schedule.
// R5 showed LDS-read windows and MFMA windows were serialized by 8
// barriers/tile (MfmaUtil 49% = MFMA/(MFMA+LDS)). Now 2 barriers/tile:
// mid-BAR protects the B-region overwrite, end-BAR+counted vmcnt protects
// the buffer flip. A-reads m2..m7 share one scheduling region with the MFMA
// clusters -> LDS pipe overlaps MFMA pipe.

#define M_DIM 8192
#define N_DIM 4096
#define K_DIM 4096
#define BK 64
#define NT (K_DIM / BK)   // 64 K-tiles

typedef __attribute__((ext_vector_type(8))) short bf16x8;
typedef __attribute__((ext_vector_type(4))) float f32x4;
typedef __attribute__((ext_vector_type(8))) unsigned short ushort8;

static __device__ __forceinline__ unsigned short f2bf(float f) {
    unsigned int u = __float_as_uint(f);
    return (unsigned short)((u + 0x7fffu + ((u >> 16) & 1u)) >> 16);
}
static __device__ __forceinline__ unsigned short f2bf_sgn(float f, unsigned int sg) {
    unsigned int u = __float_as_uint(f) ^ sg;
    return (unsigned short)((u + 0x7fffu + ((u >> 16) & 1u)) >> 16);
}

// ---------------- prep: x (fp32) -> xb (bf16) ----------------
__global__ __launch_bounds__(256) void cvt_x_kernel(const float* __restrict__ x,
                                                    unsigned short* __restrict__ xb) {
    int i = (blockIdx.x * 256 + threadIdx.x) * 8;
    f32x4 a = __builtin_nontemporal_load((const f32x4*)(x + i));      // read-once
    f32x4 b = __builtin_nontemporal_load((const f32x4*)(x + i + 4));
    ushort8 o;
    o[0] = f2bf(a[0]); o[1] = f2bf(a[1]); o[2] = f2bf(a[2]); o[3] = f2bf(a[3]);
    o[4] = f2bf(b[0]); o[5] = f2bf(b[1]); o[6] = f2bf(b[2]); o[7] = f2bf(b[3]);
    *(ushort8*)(xb + i) = o;   // xb re-read 16x -> keep cacheable
}

// ---------------- prep: assemble Hamilton W (bf16) ----------------
// Wb[o][i] = sign(p,q) * Wc[p^q][o&1023][i&1023], p=o>>10, q=i>>10,
// neg iff bit (p*4+q) of 0x428E.
__global__ __launch_bounds__(256) void prep_w_kernel(const float* __restrict__ Wr,
    const float* __restrict__ Wi, const float* __restrict__ Wj,
    const float* __restrict__ Wk, unsigned short* __restrict__ wb) {
    int row = blockIdx.x >> 1;
    int col = ((blockIdx.x & 1) * 256 + threadIdx.x) * 8;
    int p = row >> 10, q = col >> 10;
    int ci = p ^ q;
    const float* src = (ci == 0) ? Wr : (ci == 1) ? Wi : (ci == 2) ? Wj : Wk;
    unsigned int sg = ((0x428Eu >> (p * 4 + q)) & 1u) << 31;
    int so = (row & 1023) * 1024 + (col & 1023);
    f32x4 a = *(const f32x4*)(src + so);
    f32x4 b = *(const f32x4*)(src + so + 4);
    ushort8 o;
    o[0] = f2bf_sgn(a[0], sg); o[1] = f2bf_sgn(a[1], sg);
    o[2] = f2bf_sgn(a[2], sg); o[3] = f2bf_sgn(a[3], sg);
    o[4] = f2bf_sgn(b[0], sg); o[5] = f2bf_sgn(b[1], sg);
    o[6] = f2bf_sgn(b[2], sg); o[7] = f2bf_sgn(b[3], sg);
    *(ushort8*)(wb + row * 4096 + col) = o;
}

// ---------------- main GEMM: 256^2, 2-barrier merged-window ----------------
#define GLD16(gp, lp) __builtin_amdgcn_global_load_lds( \
    (const __attribute__((address_space(1))) void*)(gp), \
    (__attribute__((address_space(3))) void*)(lp), 16, 0, 0)

#define BAR() do { asm volatile("" ::: "memory"); \
                   __builtin_amdgcn_s_barrier(); \
                   asm volatile("" ::: "memory"); } while (0)
#define VM(n) asm volatile("s_waitcnt vmcnt(" #n ")" ::: "memory")

static __device__ __forceinline__ f32x4 MF(bf16x8 a, bf16x8 b, f32x4 c) {
    return __builtin_amdgcn_mfma_f32_16x16x32_bf16(a, b, c, 0, 0, 0);
}

__global__ __launch_bounds__(512, 2) void qgemm_bf16(
    const unsigned short* __restrict__ A, const unsigned short* __restrict__ B,
    const float* __restrict__ bias, float* __restrict__ out)
{
    // [buf][A=0/B=1][half][128 rows][64 shorts] = 128 KiB.
    // Content swizzle: linear slot s at row r holds logical k-slot s^(r&7)
    // (16B slots): pre-swizzled global SOURCE + swizzled ds_read (rule #21).
    __shared__ __align__(16) unsigned short Lsh[2][2][2][128 * 64];

    int bid = blockIdx.x;
    int cpx = gridDim.x >> 3;                 // 512/8 = 64, bijective
    int wg  = (bid & 7) * cpx + (bid >> 3);
    int brow = (wg >> 4) * 256;               // 32 M-tiles
    int bcol = (wg & 15) * 256;               // 16 N-tiles

    int tid   = threadIdx.x;
    int lane  = tid & 63;
    int wid   = tid >> 6;
    int hA    = wid >> 2;                     // wave's A half (128 rows)
    int nb    = wid & 3;                      // wave's 64-col B band
    int hB    = nb >> 1;
    int rB0   = (nb & 1) << 6;
    int fr    = lane & 15;
    int fslot = lane >> 4;                    // 0..3

    const unsigned short* Ag = A + (size_t)brow * K_DIM;
    const unsigned short* Bg = B + (size_t)bcol * K_DIM;

    f32x4 acc[8][4] = {};

    auto stage = [&](int buf, int ab, int half, int t) {
        const unsigned short* g = (ab ? Bg : Ag) + (size_t)(half << 7) * K_DIM + t * BK;
        unsigned short* l = &Lsh[buf][ab][half][0];
        #pragma unroll
        for (int i = 0; i < 2; ++i) {
            int c = i * 512 + tid;            // 16B chunk: row=c>>3, slot=c&7
            int r = c >> 3, s = c & 7;
            GLD16(g + (size_t)r * K_DIM + ((s ^ (r & 7)) << 3), l + (c << 3));
        }
    };
    auto rdA = [&](int buf, int mi, int ks) -> bf16x8 {
        int r = mi * 16 + fr;
        int slot = (ks * 4 + fslot) ^ (r & 7);
        return *(const bf16x8*)((const char*)&Lsh[buf][0][hA][0] + r * 128 + (slot << 4));
    };
    auto rdB = [&](int buf, int ni, int ks) -> bf16x8 {
        int r = rB0 + ni * 16 + fr;
        int slot = (ks * 4 + fslot) ^ (r & 7);
        return *(const bf16x8*)((const char*)&Lsh[buf][1][hB][0] + r * 128 + (slot << 4));
    };

    bf16x8 bfrag[4][2];

    // Prologue: tile0 A+B into buf0 (8 loads), tile1 B into buf1 (4 loads).
    stage(0, 0, 0, 0); stage(0, 0, 1, 0); stage(0, 1, 0, 0); stage(0, 1, 1, 0);
    stage(1, 1, 0, 1); stage(1, 1, 1, 1);
    VM(4); BAR();

    for (int t = 0; t < NT; ++t) {
        int buf = t & 1;

        // ---- window 0: stage A(t+1) (buf^1 A-region: fully consumed by
        //      tile t-1 before entry BAR); read all B frags + A m0,m1;
        //      MFMA m0,m1 ----
        if (t + 1 < NT) { stage(buf ^ 1, 0, 0, t + 1); stage(buf ^ 1, 0, 1, t + 1); }
        #pragma unroll
        for (int ni = 0; ni < 4; ++ni) {
            bfrag[ni][0] = rdB(buf, ni, 0);
            bfrag[ni][1] = rdB(buf, ni, 1);
        }
        {
            bf16x8 x0 = rdA(buf, 0, 0), x1 = rdA(buf, 0, 1);
            bf16x8 x2 = rdA(buf, 1, 0), x3 = rdA(buf, 1, 1);
            __builtin_amdgcn_s_setprio(1);
            #pragma unroll
            for (int ni = 0; ni < 4; ++ni) acc[0][ni] = MF(x0, bfrag[ni][0], acc[0][ni]);
            #pragma unroll
            for (int ni = 0; ni < 4; ++ni) acc[1][ni] = MF(x2, bfrag[ni][0], acc[1][ni]);
            #pragma unroll
            for (int ni = 0; ni < 4; ++ni) acc[0][ni] = MF(x1, bfrag[ni][1], acc[0][ni]);
            #pragma unroll
            for (int ni = 0; ni < 4; ++ni) acc[1][ni] = MF(x3, bfrag[ni][1], acc[1][ni]);
            __builtin_amdgcn_s_setprio(0);
        }
        BAR();  // all waves done reading B-region -> safe to overwrite it

        // ---- merged window: stage B(t+2) into current buf's B-region;
        //      A-reads m2..m7 interleave freely with MFMA clusters (no
        //      barriers; disjoint LDS regions vs in-flight staging) ----
        if (t + 2 < NT) { stage(buf, 1, 0, t + 2); stage(buf, 1, 1, t + 2); }
        {
            bf16x8 x0 = rdA(buf, 2, 0), x1 = rdA(buf, 2, 1);
            bf16x8 x2 = rdA(buf, 3, 0), x3 = rdA(buf, 3, 1);
            __builtin_amdgcn_s_setprio(1);
            #pragma unroll
            for (int ni = 0; ni < 4; ++ni) acc[2][ni] = MF(x0, bfrag[ni][0], acc[2][ni]);
            #pragma unroll
            for (int ni = 0; ni < 4; ++ni) acc[3][ni] = MF(x2, bfrag[ni][0], acc[3][ni]);
            #pragma unroll
            for (int ni = 0; ni < 4; ++ni) acc[2][ni] = MF(x1, bfrag[ni][1], acc[2][ni]);
            #pragma unroll
            for (int ni = 0; ni < 4; ++ni) acc[3][ni] = MF(x3, bfrag[ni][1], acc[3][ni]);
            __builtin_amdgcn_s_setprio(0);
        }
        {
            bf16x8 x0 = rdA(buf, 4, 0), x1 = rdA(buf, 4, 1);
            bf16x8 x2 = rdA(buf, 5, 0), x3 = rdA(buf, 5, 1);
            __builtin_amdgcn_s_setprio(1);
            #pragma unroll
            for (int ni = 0; ni < 4; ++ni) acc[4][ni] = MF(x0, bfrag[ni][0], acc[4][ni]);
            #pragma unroll
            for (int ni = 0; ni < 4; ++ni) acc[5][ni] = MF(x2, bfrag[ni][0], acc[5][ni]);
            #pragma unroll
            for (int ni = 0; ni < 4; ++ni) acc[4][ni] = MF(x1, bfrag[ni][1], acc[4][ni]);
            #pragma unroll
            for (int ni = 0; ni < 4; ++ni) acc[5][ni] = MF(x3, bfrag[ni][1], acc[5][ni]);
            __builtin_amdgcn_s_setprio(0);
        }
        {
            bf16x8 x0 = rdA(buf, 6, 0), x1 = rdA(buf, 6, 1);
            bf16x8 x2 = rdA(buf, 7, 0), x3 = rdA(buf, 7, 1);
            __builtin_amdgcn_s_setprio(1);
            #pragma unroll
            for (int ni = 0; ni < 4; ++ni) acc[6][ni] = MF(x0, bfrag[ni][0], acc[6][ni]);
            #pragma unroll
            for (int ni = 0; ni < 4; ++ni) acc[7][ni] = MF(x2, bfrag[ni][0], acc[7][ni]);
            #pragma unroll
            for (int ni = 0; ni < 4; ++ni) acc[6][ni] = MF(x1, bfrag[ni][1], acc[6][ni]);
            #pragma unroll
            for (int ni = 0; ni < 4; ++ni) acc[7][ni] = MF(x3, bfrag[ni][1], acc[7][ni]);
            __builtin_amdgcn_s_setprio(0);
        }
        // Retire A(t+1)+B(t+1); leave the 4 newest (B(t+2)) in flight.
        if (t < NT - 2) { VM(4); } else { VM(0); }
        BAR();
    }

    // epilogue: C/D layout col=lane&15, row=(lane>>4)*4+reg.
    int cr = (lane >> 4) << 2;
    int cc = lane & 15;
    #pragma unroll
    for (int ni = 0; ni < 4; ++ni) {
        int col = bcol + nb * 64 + ni * 16 + cc;
        float bv = bias[col];
        #pragma unroll
        for (int mi = 0; mi < 8; ++mi) {
            int r0 = brow + hA * 128 + mi * 16 + cr;
            #pragma unroll
            for (int r = 0; r < 4; ++r)
                __builtin_nontemporal_store(acc[mi][ni][r] + bv,
                                            &out[(size_t)(r0 + r) * N_DIM + col]);
        }
    }
}

// ---------------- fallback: reg-staged, no workspace (round-3, known-good) --
#define FBM 128
#define FBN 128
#define FBK 64
__global__ __launch_bounds__(256) void qgemm_fb(const float* __restrict__ x,
    const float* __restrict__ Wr, const float* __restrict__ Wi,
    const float* __restrict__ Wj, const float* __restrict__ Wk,
    const float* __restrict__ bias, float* __restrict__ out)
{
    __shared__ unsigned short As[FBM * FBK];
    __shared__ unsigned short Bs[FBN * FBK];

    int bid = blockIdx.x;
    int cpx = gridDim.x >> 3;
    int wg = (bid & 7) * cpx + (bid >> 3);
    int brow = (wg >> 5) * FBM;
    int bcol = (wg & 31) * FBN;

    int tid = threadIdx.x;
    int lane = tid & 63;
    int wv = tid >> 6;
    int wm = (wv >> 1) << 6;
    int wn = (wv & 1) << 6;
    int fr = lane & 15;
    int fk = (lane >> 4) << 3;

    int p = bcol >> 10;
    f32x4 acc[4][4] = {};

    for (int kt = 0; kt < K_DIM / FBK; ++kt) {
        int k0 = kt * FBK;
        int q = k0 >> 10;
        int ci = p ^ q;
        const float* wsrc = (ci == 0) ? Wr : (ci == 1) ? Wi : (ci == 2) ? Wj : Wk;
        unsigned int sg = ((0x428Eu >> (p * 4 + q)) & 1u) << 31;

        __syncthreads();
        #pragma unroll
        for (int i = 0; i < 4; ++i) {
            int c = i * 256 + tid;
            int row = c >> 3, colo = (c & 7) << 3;
            const float* s = x + (size_t)(brow + row) * K_DIM + k0 + colo;
            float4 a = *(const float4*)s;
            float4 b = *(const float4*)(s + 4);
            ushort8 o;
            o[0] = f2bf(a.x); o[1] = f2bf(a.y); o[2] = f2bf(a.z); o[3] = f2bf(a.w);
            o[4] = f2bf(b.x); o[5] = f2bf(b.y); o[6] = f2bf(b.z); o[7] = f2bf(b.w);
            *(ushort8*)(&As[c << 3]) = o;
        }
        #pragma unroll
        for (int i = 0; i < 4; ++i) {
            int c = i * 256 + tid;
            int row = c >> 3, colo = (c & 7) << 3;
            const float* s = wsrc + ((bcol + row) & 1023) * 1024 + ((k0 + colo) & 1023);
            float4 a = *(const float4*)s;
            float4 b = *(const float4*)(s + 4);
            ushort8 o;
            o[0] = f2bf_sgn(a.x, sg); o[1] = f2bf_sgn(a.y, sg);
            o[2] = f2bf_sgn(a.z, sg); o[3] = f2bf_sgn(a.w, sg);
            o[4] = f2bf_sgn(b.x, sg); o[5] = f2bf_sgn(b.y, sg);
            o[6] = f2bf_sgn(b.z, sg); o[7] = f2bf_sgn(b.w, sg);
            *(ushort8*)(&Bs[c << 3]) = o;
        }
        __syncthreads();

        #pragma unroll
        for (int ks = 0; ks < 2; ++ks) {
            bf16x8 af[4], bfr[4];
            #pragma unroll
            for (int m = 0; m < 4; ++m)
                af[m] = *(const bf16x8*)(&As[(wm + m * 16 + fr) * FBK + ks * 32 + fk]);
            #pragma unroll
            for (int n = 0; n < 4; ++n)
                bfr[n] = *(const bf16x8*)(&Bs[(wn + n * 16 + fr) * FBK + ks * 32 + fk]);
            #pragma unroll
            for (int m = 0; m < 4; ++m)
                #pragma unroll
                for (int n = 0; n < 4; ++n)
                    acc[m][n] = __builtin_amdgcn_mfma_f32_16x16x32_bf16(
                        af[m], bfr[n], acc[m][n], 0, 0, 0);
        }
    }

    int cr = (lane >> 4) << 2;
    int cc = lane & 15;
    #pragma unroll
    for (int n = 0; n < 4; ++n) {
        int col = bcol + wn + n * 16 + cc;
        float bv = bias[col];
        #pragma unroll
        for (int m = 0; m < 4; ++m) {
            int r0 = brow + wm + m * 16 + cr;
            #pragma unroll
            for (int r = 0; r < 4; ++r)
                out[(size_t)(r0 + r) * N_DIM + col] = acc[m][n][r] + bv;
        }
    }
}

extern "C" void kernel_launch(void* const* d_in, const int* in_sizes, int n_in,
                              void* d_out, int out_size, void* d_ws, size_t ws_size,
                              hipStream_t stream) {
    const float* x    = (const float*)d_in[0];
    const float* Wr   = (const float*)d_in[1];
    const float* Wi   = (const float*)d_in[2];
    const float* Wj   = (const float*)d_in[3];
    const float* Wk   = (const float*)d_in[4];
    const float* bias = (const float*)d_in[5];
    float* out = (float*)d_out;

    const size_t xb_bytes = (size_t)M_DIM * K_DIM * 2;  // 64 MiB
    const size_t wb_bytes = (size_t)N_DIM * K_DIM * 2;  // 32 MiB

    if (ws_size >= xb_bytes + wb_bytes) {
        unsigned short* xb = (unsigned short*)d_ws;
        unsigned short* wb = (unsigned short*)((char*)d_ws + xb_bytes);
        cvt_x_kernel<<<(M_DIM * K_DIM) / 2048, 256, 0, stream>>>(x, xb);
        prep_w_kernel<<<N_DIM * 2, 256, 0, stream>>>(Wr, Wi, Wj, Wk, wb);
        const int n_blocks = (M_DIM / 256) * (N_DIM / 256);  // 512
        qgemm_bf16<<<n_blocks, 512, 0, stream>>>(xb, wb, bias, out);
    } else {
        const int n_blocks = (M_DIM / FBM) * (N_DIM / FBN);  // 2048
        qgemm_fb<<<n_blocks, 256, 0, stream>>>(x, Wr, Wi, Wj, Wk, bias, out);
    }
}

// Round 8
// 271.366 us; speedup vs baseline: 1.5770x; 1.0091x over previous
//
#include <hip/hip_runtime.h>
#include <hip/hip_bf16.h>

// QuaternionLinear = one 8192x4096x4096 GEMM vs Hamilton-assembled W.
// Round 8: explicit per-wave pipelining. R7 showed MFMA / LDS-read / VALU
// addr-calc serialized per wave (4575 cyc/tile = 2483 MFMA + ~1800 LDS +
// ~960 VALU). Changes: (1) all ds_read addresses precomputed as 4 per-lane
// base offsets + compile-time immediates (addr VALU ~70 -> ~6 per tile);
// (2) A-pair(k+1) reads issued BEFORE MFMA cluster(k) so the LDS pipe runs
// under the matrix pipe. Barriers/vmcnt unchanged from the verified R7.

#define M_DIM 8192
#define N_DIM 4096
#define K_DIM 4096
#define BK 64
#define NT (K_DIM / BK)   // 64 K-tiles

typedef __attribute__((ext_vector_type(8))) short bf16x8;
typedef __attribute__((ext_vector_type(4))) float f32x4;
typedef __attribute__((ext_vector_type(8))) unsigned short ushort8;

static __device__ __forceinline__ unsigned short f2bf(float f) {
    unsigned int u = __float_as_uint(f);
    return (unsigned short)((u + 0x7fffu + ((u >> 16) & 1u)) >> 16);
}
static __device__ __forceinline__ unsigned short f2bf_sgn(float f, unsigned int sg) {
    unsigned int u = __float_as_uint(f) ^ sg;
    return (unsigned short)((u + 0x7fffu + ((u >> 16) & 1u)) >> 16);
}

// ---------------- prep: x (fp32) -> xb (bf16) ----------------
__global__ __launch_bounds__(256) void cvt_x_kernel(const float* __restrict__ x,
                                                    unsigned short* __restrict__ xb) {
    int i = (blockIdx.x * 256 + threadIdx.x) * 8;
    f32x4 a = __builtin_nontemporal_load((const f32x4*)(x + i));      // read-once
    f32x4 b = __builtin_nontemporal_load((const f32x4*)(x + i + 4));
    ushort8 o;
    o[0] = f2bf(a[0]); o[1] = f2bf(a[1]); o[2] = f2bf(a[2]); o[3] = f2bf(a[3]);
    o[4] = f2bf(b[0]); o[5] = f2bf(b[1]); o[6] = f2bf(b[2]); o[7] = f2bf(b[3]);
    *(ushort8*)(xb + i) = o;   // xb re-read 16x -> keep cacheable
}

// ---------------- prep: assemble Hamilton W (bf16) ----------------
// Wb[o][i] = sign(p,q) * Wc[p^q][o&1023][i&1023], p=o>>10, q=i>>10,
// neg iff bit (p*4+q) of 0x428E.
__global__ __launch_bounds__(256) void prep_w_kernel(const float* __restrict__ Wr,
    const float* __restrict__ Wi, const float* __restrict__ Wj,
    const float* __restrict__ Wk, unsigned short* __restrict__ wb) {
    int row = blockIdx.x >> 1;
    int col = ((blockIdx.x & 1) * 256 + threadIdx.x) * 8;
    int p = row >> 10, q = col >> 10;
    int ci = p ^ q;
    const float* src = (ci == 0) ? Wr : (ci == 1) ? Wi : (ci == 2) ? Wj : Wk;
    unsigned int sg = ((0x428Eu >> (p * 4 + q)) & 1u) << 31;
    int so = (row & 1023) * 1024 + (col & 1023);
    f32x4 a = *(const f32x4*)(src + so);
    f32x4 b = *(const f32x4*)(src + so + 4);
    ushort8 o;
    o[0] = f2bf_sgn(a[0], sg); o[1] = f2bf_sgn(a[1], sg);
    o[2] = f2bf_sgn(a[2], sg); o[3] = f2bf_sgn(a[3], sg);
    o[4] = f2bf_sgn(b[0], sg); o[5] = f2bf_sgn(b[1], sg);
    o[6] = f2bf_sgn(b[2], sg); o[7] = f2bf_sgn(b[3], sg);
    *(ushort8*)(wb + row * 4096 + col) = o;
}

// ---------------- main GEMM: 256^2, pipelined merged-window ----------------
#define GLD16(gp, lp) __builtin_amdgcn_global_load_lds( \
    (const __attribute__((address_space(1))) void*)(gp), \
    (__attribute__((address_space(3))) void*)(lp), 16, 0, 0)

#define BAR() do { asm volatile("" ::: "memory"); \
                   __builtin_amdgcn_s_barrier(); \
                   asm volatile("" ::: "memory"); } while (0)
#define VM(n) asm volatile("s_waitcnt vmcnt(" #n ")" ::: "memory")

static __device__ __forceinline__ f32x4 MF(bf16x8 a, bf16x8 b, f32x4 c) {
    return __builtin_amdgcn_mfma_f32_16x16x32_bf16(a, b, c, 0, 0, 0);
}

__global__ __launch_bounds__(512, 2) void qgemm_bf16(
    const unsigned short* __restrict__ A, const unsigned short* __restrict__ B,
    const float* __restrict__ bias, float* __restrict__ out)
{
    // [buf][A=0/B=1][half][128 rows][64 shorts] = 128 KiB.
    // Content swizzle: linear 16B slot s at row r holds logical k-slot
    // s^(r&7): pre-swizzled global SOURCE + swizzled ds_read (rule #21).
    __shared__ __align__(16) unsigned short Lsh[2][2][2][128 * 64];

    int bid = blockIdx.x;
    int cpx = gridDim.x >> 3;                 // 512/8 = 64, bijective
    int wg  = (bid & 7) * cpx + (bid >> 3);
    int brow = (wg >> 4) * 256;               // 32 M-tiles
    int bcol = (wg & 15) * 256;               // 16 N-tiles

    int tid   = threadIdx.x;
    int lane  = tid & 63;
    int wid   = tid >> 6;
    int hA    = wid >> 2;                     // wave's A half (128 rows)
    int nb    = wid & 3;                      // wave's 64-col B band
    int hB    = nb >> 1;
    int rB0   = (nb & 1) << 6;
    int fr    = lane & 15;
    int fslot = lane >> 4;                    // 0..3
    unsigned e = (unsigned)(fr & 7);

    const unsigned short* Ag = A + (size_t)brow * K_DIM;
    const unsigned short* Bg = B + (size_t)bcol * K_DIM;
    const char* LshB = (const char*)&Lsh[0][0][0][0];

    // Per-lane precomputed read offsets (bytes). All ds_reads become
    // base + compile-time immediate. ks=1 base = ks=0 base ^ 64
    // (slot(ks1) = slot(ks0)^4); buf toggle = ^0x10000.
    unsigned oA0 = (unsigned)hA * 16384u + (unsigned)fr * 128u
                 + ((((unsigned)fslot) ^ e) << 4);
    unsigned oA1 = oA0 ^ 64u;
    unsigned oB0 = 32768u + (unsigned)hB * 16384u
                 + (unsigned)(rB0 + fr) * 128u + ((((unsigned)fslot) ^ e) << 4);
    unsigned oB1 = oB0 ^ 64u;

    f32x4 acc[8][4] = {};

    auto stage = [&](int buf, int ab, int half, int t) {
        const unsigned short* g = (ab ? Bg : Ag) + (size_t)(half << 7) * K_DIM + t * BK;
        unsigned short* l = &Lsh[buf][ab][half][0];
        #pragma unroll
        for (int i = 0; i < 2; ++i) {
            int c = i * 512 + tid;            // 16B chunk: row=c>>3, slot=c&7
            int r = c >> 3, s = c & 7;
            GLD16(g + (size_t)r * K_DIM + ((s ^ (r & 7)) << 3), l + (c << 3));
        }
    };
    auto RD = [&](unsigned off) -> bf16x8 {
        return *(const bf16x8*)(LshB + off);
    };

    // MFMA cluster for acc rows ra, rb with A frags (xa0,xa1)=(ks0,ks1) of
    // row-block ra and (xb0,xb1) of row-block rb.
#define CLUSTER(xa0, xa1, xb0, xb1, ra, rb)                                   \
    do {                                                                      \
        __builtin_amdgcn_s_setprio(1);                                        \
        _Pragma("unroll")                                                     \
        for (int ni = 0; ni < 4; ++ni) acc[ra][ni] = MF(xa0, bf0[ni], acc[ra][ni]); \
        _Pragma("unroll")                                                     \
        for (int ni = 0; ni < 4; ++ni) acc[rb][ni] = MF(xb0, bf0[ni], acc[rb][ni]); \
        _Pragma("unroll")                                                     \
        for (int ni = 0; ni < 4; ++ni) acc[ra][ni] = MF(xa1, bf1[ni], acc[ra][ni]); \
        _Pragma("unroll")                                                     \
        for (int ni = 0; ni < 4; ++ni) acc[rb][ni] = MF(xb1, bf1[ni], acc[rb][ni]); \
        __builtin_amdgcn_s_setprio(0);                                        \
    } while (0)

    // Prologue: tile0 A+B into buf0 (8 loads), tile1 B into buf1 (4 loads).
    stage(0, 0, 0, 0); stage(0, 0, 1, 0); stage(0, 1, 0, 0); stage(0, 1, 1, 0);
    stage(1, 1, 0, 1); stage(1, 1, 1, 1);
    VM(4); BAR();

    for (int t = 0; t < NT; ++t) {
        bf16x8 bf0[4], bf1[4];

        // ---- entry window: issue all B reads + A pair0; stage A(t+1);
        //      issue A pair1 read-ahead; MFMA pair0 ----
        #pragma unroll
        for (int ni = 0; ni < 4; ++ni) {
            bf0[ni] = RD(oB0 + (unsigned)(ni * 2048));
            bf1[ni] = RD(oB1 + (unsigned)(ni * 2048));
        }
        bf16x8 p0a0 = RD(oA0), p0a1 = RD(oA1);
        bf16x8 p0b0 = RD(oA0 + 2048u), p0b1 = RD(oA1 + 2048u);
        if (t + 1 < NT) { stage((t & 1) ^ 1, 0, 0, t + 1); stage((t & 1) ^ 1, 0, 1, t + 1); }
        bf16x8 p1a0 = RD(oA0 + 4096u), p1a1 = RD(oA1 + 4096u);
        bf16x8 p1b0 = RD(oA0 + 6144u), p1b1 = RD(oA1 + 6144u);
        CLUSTER(p0a0, p0a1, p0b0, p0b1, 0, 1);
        BAR();  // all waves done with B-region reads -> safe to overwrite

        // ---- merged window: stage B(t+2) into current buf's B-region;
        //      read-ahead pair(k+1) before MFMA pair(k) ----
        if (t + 2 < NT) { stage(t & 1, 1, 0, t + 2); stage(t & 1, 1, 1, t + 2); }
        bf16x8 p2a0 = RD(oA0 + 8192u),  p2a1 = RD(oA1 + 8192u);
        bf16x8 p2b0 = RD(oA0 + 10240u), p2b1 = RD(oA1 + 10240u);
        CLUSTER(p1a0, p1a1, p1b0, p1b1, 2, 3);
        bf16x8 p3a0 = RD(oA0 + 12288u), p3a1 = RD(oA1 + 12288u);
        bf16x8 p3b0 = RD(oA0 + 14336u), p3b1 = RD(oA1 + 14336u);
        CLUSTER(p2a0, p2a1, p2b0, p2b1, 4, 5);
        CLUSTER(p3a0, p3a1, p3b0, p3b1, 6, 7);

        // Retire A(t+1)+B(t+1); leave the 4 newest (B(t+2)) in flight.
        if (t < NT - 2) { VM(4); } else { VM(0); }
        BAR();
        oA0 ^= 0x10000u; oA1 ^= 0x10000u; oB0 ^= 0x10000u; oB1 ^= 0x10000u;
    }
#undef CLUSTER

    // epilogue: C/D layout col=lane&15, row=(lane>>4)*4+reg.
    int cr = (lane >> 4) << 2;
    int cc = lane & 15;
    #pragma unroll
    for (int ni = 0; ni < 4; ++ni) {
        int col = bcol + nb * 64 + ni * 16 + cc;
        float bv = bias[col];
        #pragma unroll
        for (int mi = 0; mi < 8; ++mi) {
            int r0 = brow + hA * 128 + mi * 16 + cr;
            #pragma unroll
            for (int r = 0; r < 4; ++r)
                __builtin_nontemporal_store(acc[mi][ni][r] + bv,
                                            &out[(size_t)(r0 + r) * N_DIM + col]);
        }
    }
}

// ---------------- fallback: reg-staged, no workspace (round-3, known-good) --
#define FBM 128
#define FBN 128
#define FBK 64
__global__ __launch_bounds__(256) void qgemm_fb(const float* __restrict__ x,
    const float* __restrict__ Wr, const float* __restrict__ Wi,
    const float* __restrict__ Wj, const float* __restrict__ Wk,
    const float* __restrict__ bias, float* __restrict__ out)
{
    __shared__ unsigned short As[FBM * FBK];
    __shared__ unsigned short Bs[FBN * FBK];

    int bid = blockIdx.x;
    int cpx = gridDim.x >> 3;
    int wg = (bid & 7) * cpx + (bid >> 3);
    int brow = (wg >> 5) * FBM;
    int bcol = (wg & 31) * FBN;

    int tid = threadIdx.x;
    int lane = tid & 63;
    int wv = tid >> 6;
    int wm = (wv >> 1) << 6;
    int wn = (wv & 1) << 6;
    int fr = lane & 15;
    int fk = (lane >> 4) << 3;

    int p = bcol >> 10;
    f32x4 acc[4][4] = {};

    for (int kt = 0; kt < K_DIM / FBK; ++kt) {
        int k0 = kt * FBK;
        int q = k0 >> 10;
        int ci = p ^ q;
        const float* wsrc = (ci == 0) ? Wr : (ci == 1) ? Wi : (ci == 2) ? Wj : Wk;
        unsigned int sg = ((0x428Eu >> (p * 4 + q)) & 1u) << 31;

        __syncthreads();
        #pragma unroll
        for (int i = 0; i < 4; ++i) {
            int c = i * 256 + tid;
            int row = c >> 3, colo = (c & 7) << 3;
            const float* s = x + (size_t)(brow + row) * K_DIM + k0 + colo;
            float4 a = *(const float4*)s;
            float4 b = *(const float4*)(s + 4);
            ushort8 o;
            o[0] = f2bf(a.x); o[1] = f2bf(a.y); o[2] = f2bf(a.z); o[3] = f2bf(a.w);
            o[4] = f2bf(b.x); o[5] = f2bf(b.y); o[6] = f2bf(b.z); o[7] = f2bf(b.w);
            *(ushort8*)(&As[c << 3]) = o;
        }
        #pragma unroll
        for (int i = 0; i < 4; ++i) {
            int c = i * 256 + tid;
            int row = c >> 3, colo = (c & 7) << 3;
            const float* s = wsrc + ((bcol + row) & 1023) * 1024 + ((k0 + colo) & 1023);
            float4 a = *(const float4*)s;
            float4 b = *(const float4*)(s + 4);
            ushort8 o;
            o[0] = f2bf_sgn(a.x, sg); o[1] = f2bf_sgn(a.y, sg);
            o[2] = f2bf_sgn(a.z, sg); o[3] = f2bf_sgn(a.w, sg);
            o[4] = f2bf_sgn(b.x, sg); o[5] = f2bf_sgn(b.y, sg);
            o[6] = f2bf_sgn(b.z, sg); o[7] = f2bf_sgn(b.w, sg);
            *(ushort8*)(&Bs[c << 3]) = o;
        }
        __syncthreads();

        #pragma unroll
        for (int ks = 0; ks < 2; ++ks) {
            bf16x8 af[4], bfr[4];
            #pragma unroll
            for (int m = 0; m < 4; ++m)
                af[m] = *(const bf16x8*)(&As[(wm + m * 16 + fr) * FBK + ks * 32 + fk]);
            #pragma unroll
            for (int n = 0; n < 4; ++n)
                bfr[n] = *(const bf16x8*)(&Bs[(wn + n * 16 + fr) * FBK + ks * 32 + fk]);
            #pragma unroll
            for (int m = 0; m < 4; ++m)
                #pragma unroll
                for (int n = 0; n < 4; ++n)
                    acc[m][n] = __builtin_amdgcn_mfma_f32_16x16x32_bf16(
                        af[m], bfr[n], acc[m][n], 0, 0, 0);
        }
    }

    int cr = (lane >> 4) << 2;
    int cc = lane & 15;
    #pragma unroll
    for (int n = 0; n < 4; ++n) {
        int col = bcol + wn + n * 16 + cc;
        float bv = bias[col];
        #pragma unroll
        for (int m = 0; m < 4; ++m) {
            int r0 = brow + wm + m * 16 + cr;
            #pragma unroll
            for (int r = 0; r < 4; ++r)
                out[(size_t)(r0 + r) * N_DIM + col] = acc[m][n][r] + bv;
        }
    }
}

extern "C" void kernel_launch(void* const* d_in, const int* in_sizes, int n_in,
                              void* d_out, int out_size, void* d_ws, size_t ws_size,
                              hipStream_t stream) {
    const float* x    = (const float*)d_in[0];
    const float* Wr   = (const float*)d_in[1];
    const float* Wi   = (const float*)d_in[2];
    const float* Wj   = (const float*)d_in[3];
    const float* Wk   = (const float*)d_in[4];
    const float* bias = (const float*)d_in[5];
    float* out = (float*)d_out;

    const size_t xb_bytes = (size_t)M_DIM * K_DIM * 2;  // 64 MiB
    const size_t wb_bytes = (size_t)N_DIM * K_DIM * 2;  // 32 MiB

    if (ws_size >= xb_bytes + wb_bytes) {
        unsigned short* xb = (unsigned short*)d_ws;
        unsigned short* wb = (unsigned short*)((char*)d_ws + xb_bytes);
        cvt_x_kernel<<<(M_DIM * K_DIM) / 2048, 256, 0, stream>>>(x, xb);
        prep_w_kernel<<<N_DIM * 2, 256, 0, stream>>>(Wr, Wi, Wj, Wk, wb);
        const int n_blocks = (M_DIM / 256) * (N_DIM / 256);  // 512
        qgemm_bf16<<<n_blocks, 512, 0, stream>>>(xb, wb, bias, out);
    } else {
        const int n_blocks = (M_DIM / FBM) * (N_DIM / FBN);  // 2048
        qgemm_fb<<<n_blocks, 256, 0, stream>>>(x, Wr, Wi, Wj, Wk, bias, out);
    }
}